// Round 5
// baseline (300.384 us; speedup 1.0000x reference)
//
#include <hip/hip_runtime.h>
#include <hip/hip_bf16.h>

constexpr int Bn  = 4;
constexpr int Sn  = 2048;
constexpr int NIN = 1024;
constexpr int Hn  = 8;
constexpr int DKn = 128;
constexpr int NL  = Hn * DKn;      // 1024
constexpr int Mrows = Bn * Sn;     // 8192
constexpr int KTILES = NIN / 32;   // 32

// Q pre-scale so attention scores need only exp2: p = 2^(q~ . k)
#define QSCL 0.1275429916f         // log2(e)/sqrt(128)

typedef __bf16 bf16x8 __attribute__((ext_vector_type(8)));
typedef float  f32x4  __attribute__((ext_vector_type(4)));

__device__ __forceinline__ unsigned short f2bf(float f) {   // RNE f32->bf16 bits
    unsigned u = __builtin_bit_cast(unsigned, f);
    u += 0x7FFFu + ((u >> 16) & 1u);
    return (unsigned short)(u >> 16);
}
__device__ __forceinline__ unsigned pk2(float lo, float hi) {
    return (unsigned)f2bf(lo) | ((unsigned)f2bf(hi) << 16);
}

__device__ __forceinline__ void stage16(const void* g, void* l) {
    __builtin_amdgcn_global_load_lds(
        (const __attribute__((address_space(1))) unsigned int*)g,
        (__attribute__((address_space(3))) unsigned int*)l,
        16, 0, 0);
}

// ---------- convert x (f32 row-major) -> bf16 swizzled K-panels ----------
__global__ void convert_x(const float* __restrict__ x, unsigned short* __restrict__ Ap)
{
    const int gid = blockIdx.x * 256 + threadIdx.x;
    const int e = gid * 8;
    const int row = e >> 10, k = e & 1023;
    const int tm = row >> 7, r = row & 127;
    const int kc = k >> 5, kk = k & 31;
    const float4 v0 = *(const float4*)&x[e];
    const float4 v1 = *(const float4*)&x[e + 4];
    uint4 w;
    w.x = pk2(v0.x, v0.y); w.y = pk2(v0.z, v0.w);
    w.z = pk2(v1.x, v1.y); w.w = pk2(v1.z, v1.w);
    const size_t tile = (size_t)(tm * KTILES + kc) * 8192;
    const int byte = (r * 64 + kk * 2) ^ ((r & 7) << 4);
    *(uint4*)((char*)Ap + tile + byte) = w;
}

// ---------- convert W (f32 [k][n]) -> bf16 transposed swizzled panels ----------
__global__ void convert_w(const float* __restrict__ Wq, const float* __restrict__ Wk,
                          unsigned short* __restrict__ Bp)
{
    const int tn = blockIdx.x >> 5, kc = blockIdx.x & 31;
    const int t = threadIdx.x;
    const int c = t & 127, kh = (t >> 7) * 16;
    const float* __restrict__ W = (tn < 8) ? Wq : Wk;
    const int ncol = (tn & 7) * 128 + c;
    const int k0 = kc * 32 + kh;
    float v[16];
    #pragma unroll
    for (int j = 0; j < 16; ++j)
        v[j] = W[(size_t)(k0 + j) * NL + ncol];
    uint4 w0, w1;
    w0.x = pk2(v[0], v[1]);  w0.y = pk2(v[2], v[3]);
    w0.z = pk2(v[4], v[5]);  w0.w = pk2(v[6], v[7]);
    w1.x = pk2(v[8], v[9]);  w1.y = pk2(v[10], v[11]);
    w1.z = pk2(v[12], v[13]); w1.w = pk2(v[14], v[15]);
    const size_t tbase = (size_t)blockIdx.x * 8192;
    const int b0 = (c * 64 + kh * 2) ^ ((c & 7) << 4);
    const int b1 = (c * 64 + kh * 2 + 16) ^ ((c & 7) << 4);
    *(uint4*)((char*)Bp + tbase + b0) = w0;
    *(uint4*)((char*)Bp + tbase + b1) = w1;
}

// ---------- fused projection GEMM (bf16 MFMA) + bias + activation -> bf16 Q/K ----------
__global__ __launch_bounds__(256) void gemm_kernel(
    const unsigned short* __restrict__ Ap, const unsigned short* __restrict__ Bp,
    const float* __restrict__ bq, const float* __restrict__ bk,
    unsigned short* __restrict__ Qb, unsigned short* __restrict__ Kb)
{
    __shared__ unsigned short Asm[128 * 32];
    __shared__ unsigned short Bsm[128 * 32];

    const int tid = threadIdx.x;
    const int wave = tid >> 6, lane = tid & 63;
    const int ln = lane & 15, kg = lane >> 4;
    const int wr = wave >> 1, wc = wave & 1;

    const int bid = blockIdx.x;
    const int wg = (bid & 7) * 128 + (bid >> 3);
    const int bm = wg >> 4, bn = wg & 15;

    const unsigned short* At = Ap + (size_t)bm * (KTILES * 4096);
    const unsigned short* Bt = Bp + (size_t)bn * (KTILES * 4096);

    f32x4 acc[4][4];
    #pragma unroll
    for (int m = 0; m < 4; ++m)
        #pragma unroll
        for (int n = 0; n < 4; ++n) acc[m][n] = (f32x4){0.f, 0.f, 0.f, 0.f};

    int aoff[4], boff[4];
    #pragma unroll
    for (int m = 0; m < 4; ++m) {
        const int row = wr * 64 + m * 16 + ln;
        aoff[m] = (row * 64 + kg * 16) ^ ((ln & 7) << 4);
        const int col = wc * 64 + m * 16 + ln;
        boff[m] = (col * 64 + kg * 16) ^ ((ln & 7) << 4);
    }

    for (int kc = 0; kc < KTILES; ++kc) {
        __syncthreads();
        const unsigned short* ga = At + kc * 4096;
        const unsigned short* gb = Bt + kc * 4096;
        stage16(ga + tid * 8,        Asm + tid * 8);
        stage16(ga + 2048 + tid * 8, Asm + 2048 + tid * 8);
        stage16(gb + tid * 8,        Bsm + tid * 8);
        stage16(gb + 2048 + tid * 8, Bsm + 2048 + tid * 8);
        __syncthreads();

        bf16x8 af[4], bfv[4];
        #pragma unroll
        for (int m = 0; m < 4; ++m) af[m] = *(const bf16x8*)((const char*)Asm + aoff[m]);
        #pragma unroll
        for (int n = 0; n < 4; ++n) bfv[n] = *(const bf16x8*)((const char*)Bsm + boff[n]);
        #pragma unroll
        for (int m = 0; m < 4; ++m)
            #pragma unroll
            for (int n = 0; n < 4; ++n)
                acc[m][n] = __builtin_amdgcn_mfma_f32_16x16x32_bf16(af[m], bfv[n], acc[m][n], 0, 0, 0);
    }

    const bool isQ = (bn < 8);
    const float* __restrict__ bias = isQ ? bq : bk;
    unsigned short* __restrict__ outp = isQ ? Qb : Kb;
    const int cbase = (isQ ? bn : bn - 8) * 128 + wc * 64 + (ln & ~3);
    float4 b4[4];
    #pragma unroll
    for (int n = 0; n < 4; ++n) b4[n] = *(const float4*)&bias[cbase + n * 16];
    const int i = ln & 3;

    #pragma unroll
    for (int m = 0; m < 4; ++m) {
        const size_t grow = bm * 128 + wr * 64 + m * 16 + kg * 4 + i;
        #pragma unroll
        for (int n = 0; n < 4; ++n) {
            float a0 = acc[m][n][0], a1 = acc[m][n][1], a2 = acc[m][n][2], a3 = acc[m][n][3];
            float t;
            t = __shfl_xor((i & 1) ? a0 : a1, 1); if (i & 1) a0 = t; else a1 = t;
            t = __shfl_xor((i & 1) ? a2 : a3, 1); if (i & 1) a2 = t; else a3 = t;
            t = __shfl_xor((i & 2) ? a0 : a2, 2); if (i & 2) a0 = t; else a2 = t;
            t = __shfl_xor((i & 2) ? a1 : a3, 2); if (i & 2) a1 = t; else a3 = t;
            a0 += b4[n].x; a1 += b4[n].y; a2 += b4[n].z; a3 += b4[n].w;
            float r0, r1, r2, r3;
            if (isQ) {
                r0 = tanhf(a0) * QSCL; r1 = tanhf(a1) * QSCL;
                r2 = tanhf(a2) * QSCL; r3 = tanhf(a3) * QSCL;
            } else {
                r0 = 1.0f / (1.0f + __expf(-a0)); r1 = 1.0f / (1.0f + __expf(-a1));
                r2 = 1.0f / (1.0f + __expf(-a2)); r3 = 1.0f / (1.0f + __expf(-a3));
            }
            uint2 w; w.x = pk2(r0, r1); w.y = pk2(r2, r3);
            *(uint2*)&outp[grow * NL + cbase + n * 16] = w;
        }
    }
}

// ---------- attention: LDS-shared K, two-pass recompute ----------
// Block = (b, h, 128-query tile): 8 waves x 16 queries each. K staged cooperatively
// in 64-key steps (16 KB LDS, XOR-swizzled rows, pre-swizzled global source).
// Pass A: row sums (wave-private rows -> butterfly shfl only). Pass B: recompute,
// exp2 * 1/L -> LDS csum -> one global atomic flush. Scores bounded: no max pass.
constexpr int KS = 64;
constexpr int NSTEP = Sn / KS;   // 32

__global__ __launch_bounds__(512) void attn_kernel(
    const unsigned short* __restrict__ Qb,
    const unsigned short* __restrict__ Kb, float* __restrict__ colsum)
{
    __shared__ unsigned short Ksm[KS * DKn];   // 16 KB
    __shared__ float csum[Sn];                 // 8 KB

    const int tid = threadIdx.x;
    const int wave = tid >> 6, lane = tid & 63;
    const int ln15 = lane & 15, lg = lane >> 4;
    const int h = blockIdx.y, b = blockIdx.z;
    const int q0 = blockIdx.x * 128;

    *(float4*)&csum[tid * 4] = (float4){0.f, 0.f, 0.f, 0.f};

    // wave-private Q fragments (16 queries per wave)
    bf16x8 qf[4];
    {
        const size_t ro = ((size_t)(b * Sn + q0 + wave * 16 + ln15)) * NL + h * DKn + lg * 8;
        #pragma unroll
        for (int ks = 0; ks < 4; ++ks)
            qf[ks] = *(const bf16x8*)(Qb + ro + ks * 32);
    }

    // staging: thread stages LDS bytes [tid*16] and [tid*16 + 8192].
    // LDS offset o: key = o>>8, unit_swz = (o>>4)&15, logical unit = unit_swz ^ (key&7).
    const char* kbase = (const char*)Kb + ((size_t)b * Sn * NL + h * DKn) * 2;
    int soff[2];
    #pragma unroll
    for (int cch = 0; cch < 2; ++cch) {
        const int o = tid * 16 + cch * 8192;
        const int key = o >> 8, us = (o >> 4) & 15;
        soff[cch] = key * (NL * 2) + ((us ^ (key & 7)) << 4);
    }

    // per-lane ds_read byte offsets (loop-invariant)
    int koff[4][4];
    #pragma unroll
    for (int s = 0; s < 4; ++s)
        #pragma unroll
        for (int ks = 0; ks < 4; ++ks)
            koff[s][ks] = (s * 16 + ln15) * 256 + (((ks * 4 + lg) ^ (ln15 & 7)) << 4);

    // ---- pass A: row sums ----
    float rs[4] = {0.f, 0.f, 0.f, 0.f};
    for (int step = 0; step < NSTEP; ++step) {
        __syncthreads();
        const char* src = kbase + (size_t)step * (KS * NL * 2);
        stage16(src + soff[0], (char*)Ksm + tid * 16);
        stage16(src + soff[1], (char*)Ksm + tid * 16 + 8192);
        __syncthreads();
        #pragma unroll
        for (int s = 0; s < 4; ++s) {
            bf16x8 k0 = *(const bf16x8*)((const char*)Ksm + koff[s][0]);
            bf16x8 k1 = *(const bf16x8*)((const char*)Ksm + koff[s][1]);
            bf16x8 k2 = *(const bf16x8*)((const char*)Ksm + koff[s][2]);
            bf16x8 k3 = *(const bf16x8*)((const char*)Ksm + koff[s][3]);
            f32x4 a = (f32x4){0.f, 0.f, 0.f, 0.f};
            a = __builtin_amdgcn_mfma_f32_16x16x32_bf16(qf[0], k0, a, 0, 0, 0);
            a = __builtin_amdgcn_mfma_f32_16x16x32_bf16(qf[1], k1, a, 0, 0, 0);
            a = __builtin_amdgcn_mfma_f32_16x16x32_bf16(qf[2], k2, a, 0, 0, 0);
            a = __builtin_amdgcn_mfma_f32_16x16x32_bf16(qf[3], k3, a, 0, 0, 0);
            rs[0] += exp2f(a[0]); rs[1] += exp2f(a[1]);
            rs[2] += exp2f(a[2]); rs[3] += exp2f(a[3]);
        }
    }

    // butterfly within 16-lane groups: every lane gets its 4 row totals
    float rv[4];
    #pragma unroll
    for (int j = 0; j < 4; ++j) {
        float v = rs[j];
        v += __shfl_xor(v, 1); v += __shfl_xor(v, 2);
        v += __shfl_xor(v, 4); v += __shfl_xor(v, 8);
        rv[j] = 1.0f / v;
    }

    // ---- pass B: normalized column sums ----
    for (int step = 0; step < NSTEP; ++step) {
        __syncthreads();
        const char* src = kbase + (size_t)step * (KS * NL * 2);
        stage16(src + soff[0], (char*)Ksm + tid * 16);
        stage16(src + soff[1], (char*)Ksm + tid * 16 + 8192);
        __syncthreads();
        #pragma unroll
        for (int s = 0; s < 4; ++s) {
            bf16x8 k0 = *(const bf16x8*)((const char*)Ksm + koff[s][0]);
            bf16x8 k1 = *(const bf16x8*)((const char*)Ksm + koff[s][1]);
            bf16x8 k2 = *(const bf16x8*)((const char*)Ksm + koff[s][2]);
            bf16x8 k3 = *(const bf16x8*)((const char*)Ksm + koff[s][3]);
            f32x4 a = (f32x4){0.f, 0.f, 0.f, 0.f};
            a = __builtin_amdgcn_mfma_f32_16x16x32_bf16(qf[0], k0, a, 0, 0, 0);
            a = __builtin_amdgcn_mfma_f32_16x16x32_bf16(qf[1], k1, a, 0, 0, 0);
            a = __builtin_amdgcn_mfma_f32_16x16x32_bf16(qf[2], k2, a, 0, 0, 0);
            a = __builtin_amdgcn_mfma_f32_16x16x32_bf16(qf[3], k3, a, 0, 0, 0);
            float c = exp2f(a[0]) * rv[0];
            c = fmaf(exp2f(a[1]), rv[1], c);
            c = fmaf(exp2f(a[2]), rv[2], c);
            c = fmaf(exp2f(a[3]), rv[3], c);
            c += __shfl_xor(c, 16); c += __shfl_xor(c, 32);
            if (lane < 16) atomicAdd(&csum[step * KS + s * 16 + ln15], c);
        }
    }

    __syncthreads();
    float* cs = colsum + ((size_t)(b * Hn + h)) * Sn;
    #pragma unroll
    for (int i = 0; i < 4; ++i)
        atomicAdd(&cs[tid * 4 + i], csum[tid * 4 + i]);
}

// ---------- final reduce ----------
__global__ void final_kernel(const float* __restrict__ colsum,
                             const float* __restrict__ w_fc,
                             const float* __restrict__ b_fc,
                             float* __restrict__ out)
{
    const int idx = blockIdx.x * 256 + threadIdx.x;
    if (idx >= Bn * Sn) return;
    const int b = idx / Sn, s = idx - b * Sn;
    float accv = b_fc[0];
    #pragma unroll
    for (int h = 0; h < Hn; ++h)
        accv += colsum[((size_t)(b * Hn + h)) * Sn + s] * w_fc[h] * (1.0f / Sn);
    out[idx] = accv;
}

extern "C" void kernel_launch(void* const* d_in, const int* in_sizes, int n_in,
                              void* d_out, int out_size, void* d_ws, size_t ws_size,
                              hipStream_t stream)
{
    const float* x    = (const float*)d_in[0];
    const float* Wq   = (const float*)d_in[1];
    const float* bq   = (const float*)d_in[2];
    const float* Wk   = (const float*)d_in[3];
    const float* bk   = (const float*)d_in[4];
    const float* w_fc = (const float*)d_in[5];
    const float* b_fc = (const float*)d_in[6];
    float* out = (float*)d_out;

    const size_t NE = (size_t)Mrows * NIN;
    unsigned short* Ap = (unsigned short*)d_ws;
    unsigned short* Bp = Ap + NE;
    unsigned short* Qb = Bp + (size_t)NIN * 2048;
    unsigned short* Kb = Qb + (size_t)Mrows * NL;
    float* colsum = (float*)(Kb + (size_t)Mrows * NL);

    hipMemsetAsync(colsum, 0, (size_t)Bn * Hn * Sn * sizeof(float), stream);

    convert_x<<<Mrows * NIN / 8 / 256, 256, 0, stream>>>(x, Ap);
    convert_w<<<16 * KTILES, 256, 0, stream>>>(Wq, Wk, Bp);
    gemm_kernel<<<(Mrows / 128) * (2048 / 128), 256, 0, stream>>>(Ap, Bp, bq, bk, Qb, Kb);
    attn_kernel<<<dim3(Sn / 128, Hn, Bn), 512, 0, stream>>>(Qb, Kb, colsum);
    final_kernel<<<(Bn * Sn + 255) / 256, 256, 0, stream>>>(colsum, w_fc, b_fc, out);
}